// Round 10
// baseline (101.571 us; speedup 1.0000x reference)
//
#include <hip/hip_runtime.h>

namespace {

constexpr int NB = 4, L = 4096, HC = 4, D = 1024, KW = 4;
constexpr int PAD = 6;                 // (KW-1)*DIL
constexpr float EPS = 1e-5f;
constexpr int ST = 2;                  // rows per step
constexpr int NSTEP = 16;              // steps per block
constexpr int CL = ST * NSTEP;         // 32 rows per block
constexpr int NT = L / CL;             // 128
constexpr int BDIM = 256;              // 4 waves
constexpr int NBLK = NB * HC * NT;     // 2048
constexpr int CPX = NBLK / 8;          // 256 blocks per XCD

typedef float f32x4 __attribute__((ext_vector_type(4)));

#define LGKM_BARRIER() do {                                    \
    asm volatile("s_waitcnt lgkmcnt(0)" ::: "memory");         \
    __builtin_amdgcn_s_barrier();                              \
} while (0)

__device__ __forceinline__ void stage16(const float* g, float* l) {
    __builtin_amdgcn_global_load_lds(
        (const __attribute__((address_space(1))) void*)g,
        (__attribute__((address_space(3))) void*)l, 16, 0, 0);
}

__global__ __launch_bounds__(BDIM, 6) void engram_shortconv_v10(
    const float* __restrict__ x,
    const float* __restrict__ nw,
    const float* __restrict__ cw,
    float* __restrict__ out)
{
    __shared__ float s_buf[3][ST][D];      // 24 KiB triple-buffered x
    __shared__ float s_part[PAD][4];       // 96 B wave-partials (halo)
    __shared__ float s_inv2[2][ST];
    __shared__ float s_invh[PAD];

    // Bijective XCD-chunked swizzle (2048 blocks, 8 XCDs): L-neighbor
    // (halo-sharing) blocks land on the same XCD's L2.
    const int lblk = (blockIdx.x & 7) * CPX + (blockIdx.x >> 3);
    const int t    = lblk % NT;
    const int hc   = (lblk / NT) % HC;
    const int b    = lblk / (NT * HC);
    const int l0   = t * CL;

    const int tid  = threadIdx.x;
    const int wave = tid >> 6;
    const int lane = tid & 63;

    const size_t rs = (size_t)HC * D;
    const float* xcol = x   + ((size_t)b * L * HC + (size_t)hc) * D + tid * 4;
    float*       ocol = out + ((size_t)b * L * HC + (size_t)hc) * D + tid * 4;

    // ---- issue order matters for vmcnt: weights(5), halo(6), stages(6) ----
    const float4 nw4 = *(const float4*)(nw + (size_t)hc * D + tid * 4);
    float4 cwv[4];
    #pragma unroll
    for (int j = 0; j < 4; ++j)
        cwv[j] = *(const float4*)(cw + ((size_t)hc * D + tid * 4 + j) * KW);

    float win[PAD][4];   // halo rows l0-6 .. l0-1
    #pragma unroll
    for (int r = 0; r < PAD; ++r) {
        const int l = l0 - PAD + r;
        float4 v = make_float4(0.f, 0.f, 0.f, 0.f);
        if (l >= 0) v = *(const float4*)(xcol + (size_t)l * rs);
        win[r][0] = v.x; win[r][1] = v.y; win[r][2] = v.z; win[r][3] = v.w;
    }

    #pragma unroll
    for (int s = 0; s < 3; ++s)
        #pragma unroll
        for (int r = 0; r < ST; ++r)
            stage16(xcol + (size_t)(l0 + s * ST + r) * rs, &s_buf[s][r][wave * 256]);

    // fold norm gain into conv taps
    float wk[4][4];
    {
        const float gv[4] = { nw4.x, nw4.y, nw4.z, nw4.w };
        #pragma unroll
        for (int j = 0; j < 4; ++j) {
            wk[j][0] = cwv[j].x * gv[j]; wk[j][1] = cwv[j].y * gv[j];
            wk[j][2] = cwv[j].z * gv[j]; wk[j][3] = cwv[j].w * gv[j];
        }
    }

    // ---- halo RMS: shfl-first (tiny LDS), halo read exactly once ----
    #pragma unroll
    for (int r = 0; r < PAD; ++r) {
        float ss = fmaf(win[r][0], win[r][0], fmaf(win[r][1], win[r][1],
                   fmaf(win[r][2], win[r][2], win[r][3] * win[r][3])));
        #pragma unroll
        for (int off = 32; off >= 1; off >>= 1) ss += __shfl_xor(ss, off);
        if (lane == 0) s_part[r][wave] = ss;
    }
    LGKM_BARRIER();
    if (wave == 0 && lane < PAD) {
        const float s = s_part[lane][0] + s_part[lane][1]
                      + s_part[lane][2] + s_part[lane][3];
        s_invh[lane] = rsqrtf(s * (1.0f / D) + EPS);
    }
    LGKM_BARRIER();
    #pragma unroll
    for (int r = 0; r < PAD; ++r) {
        const float iv = s_invh[r];
        win[r][0] *= iv; win[r][1] *= iv; win[r][2] *= iv; win[r][3] *= iv;
    }

    // stages 0,1 retired (stage2 may fly); cross-wave visible after barrier
    asm volatile("s_waitcnt vmcnt(2)" ::: "memory");
    __builtin_amdgcn_s_barrier();
    {   // seed s_inv2[0][0..1] from buf0 (waves 0,2 -> row0; 1,3 -> row1)
        const int row = wave & 1;
        const float* rp = &s_buf[0][row][0];
        float ss = 0.0f;
        #pragma unroll
        for (int q = 0; q < 4; ++q) {
            const f32x4 v = *(const f32x4*)(rp + lane * 4 + q * 256);
            ss = fmaf(v.x, v.x, fmaf(v.y, v.y, fmaf(v.z, v.z, fmaf(v.w, v.w, ss))));
        }
        #pragma unroll
        for (int off = 32; off >= 1; off >>= 1) ss += __shfl_xor(ss, off);
        if (lane == 0) s_inv2[0][row] = rsqrtf(ss * (1.0f / D) + EPS);
    }
    LGKM_BARRIER();

    float* p0 = &s_buf[0][0][0];
    float* p1 = &s_buf[1][0][0];
    float* p2 = &s_buf[2][0][0];

    #pragma unroll 1
    for (int s = 0; s < NSTEP; ++s) {
        // (a) reduce-ahead: rows of p1 (= stage(s+1) data) -> s_inv2[(s+1)&1]
        if (s < NSTEP - 1) {
            const int row = wave & 1;
            const float* rp = p1 + row * D;
            float ss = 0.0f;
            #pragma unroll
            for (int q = 0; q < 4; ++q) {
                const f32x4 v = *(const f32x4*)(rp + lane * 4 + q * 256);
                ss = fmaf(v.x, v.x, fmaf(v.y, v.y, fmaf(v.z, v.z, fmaf(v.w, v.w, ss))));
            }
            #pragma unroll
            for (int off = 32; off >= 1; off >>= 1) ss += __shfl_xor(ss, off);
            if (lane == 0) s_inv2[(s + 1) & 1][row] = rsqrtf(ss * (1.0f / D) + EPS);
        }

        // (b) conv math for this step's ST rows (own-slice LDS reads only)
        const int base = l0 + s * ST;
        float cur[ST][4];
        #pragma unroll
        for (int r = 0; r < ST; ++r) {
            const f32x4 v = *(const f32x4*)(p0 + r * D + tid * 4);
            const float iv = s_inv2[s & 1][r];
            cur[r][0] = v.x * iv; cur[r][1] = v.y * iv;
            cur[r][2] = v.z * iv; cur[r][3] = v.w * iv;
        }
        float ov[ST][4];
        #pragma unroll
        for (int i = 0; i < ST; ++i) {
            #pragma unroll
            for (int j = 0; j < 4; ++j) {
                float a = 0.0f;
                #pragma unroll
                for (int k = 0; k < 4; ++k) {
                    const int rel = i - 6 + 2 * k;
                    const float xv = (rel < 0) ? win[6 + rel][j] : cur[rel][j];
                    a = fmaf(wk[j][k], xv, a);
                }
                ov[i][j] = a / (1.0f + __expf(-a));
            }
        }

        // (c) rotate halo (scaled)
        #pragma unroll
        for (int r = 0; r < PAD - ST; ++r) {
            win[r][0] = win[r + ST][0]; win[r][1] = win[r + ST][1];
            win[r][2] = win[r + ST][2]; win[r][3] = win[r + ST][3];
        }
        #pragma unroll
        for (int r = 0; r < ST; ++r) {
            win[PAD - ST + r][0] = cur[r][0]; win[PAD - ST + r][1] = cur[r][1];
            win[PAD - ST + r][2] = cur[r][2]; win[PAD - ST + r][3] = cur[r][3];
        }

        // (d) stage(s+3) into p0 (just consumed) — issued BEFORE the stores
        if (s < NSTEP - 3) {
            asm volatile("s_waitcnt lgkmcnt(0)" ::: "memory");
            __builtin_amdgcn_sched_barrier(0);
            #pragma unroll
            for (int r = 0; r < ST; ++r)
                stage16(xcol + (size_t)(l0 + (s + 3) * ST + r) * rs,
                        p0 + r * D + wave * 256);
            __builtin_amdgcn_sched_barrier(0);
        }

        // stores (nontemporal: output never re-read; keep L2/L3 for x)
        #pragma unroll
        for (int i = 0; i < ST; ++i) {
            f32x4 o = { ov[i][0], ov[i][1], ov[i][2], ov[i][3] };
            __builtin_nontemporal_store(o, (f32x4*)(ocol + (size_t)(base + i) * rs));
        }

        // (e) counted vmcnt: stage(s+2) retired; newer ops stay in flight
        if (s < NSTEP - 1) {
            if (s <= NSTEP - 4)      asm volatile("s_waitcnt vmcnt(6)" ::: "memory");
            else if (s == NSTEP - 3) asm volatile("s_waitcnt vmcnt(4)" ::: "memory");
            LGKM_BARRIER();
        }

        float* tmp = p0; p0 = p1; p1 = p2; p2 = tmp;
    }
}

} // namespace

extern "C" void kernel_launch(void* const* d_in, const int* in_sizes, int n_in,
                              void* d_out, int out_size, void* d_ws, size_t ws_size,
                              hipStream_t stream) {
    const float* x  = (const float*)d_in[0];   // [B, L, HC, D] f32
    const float* nw = (const float*)d_in[1];   // [HC, D] f32
    const float* cw = (const float*)d_in[2];   // [C, 1, K] f32
    float* out = (float*)d_out;                // [B, L, HC, D] f32

    engram_shortconv_v10<<<dim3(NBLK), dim3(BDIM), 0, stream>>>(x, nw, cw, out);
}

// Round 11
// 94.109 us; speedup vs baseline: 1.0793x; 1.0793x over previous
//
#include <hip/hip_runtime.h>

namespace {

constexpr int NB = 4, L = 4096, HC = 4, D = 1024, KW = 4;
constexpr int PAD = 6;                 // (KW-1)*DIL
constexpr float EPS = 1e-5f;
constexpr int ST = 2;                  // rows per step
constexpr int NSTEP = 64;              // steps per block
constexpr int CL = ST * NSTEP;         // 128 rows per block
constexpr int NT = L / CL;             // 32
constexpr int BDIM = 256;              // 4 waves
constexpr int NBLK = NB * HC * NT;     // 512
constexpr int CPX = NBLK / 8;          // 64 blocks per XCD

typedef float f32x4 __attribute__((ext_vector_type(4)));

#define LGKM_BARRIER() do {                                    \
    asm volatile("s_waitcnt lgkmcnt(0)" ::: "memory");         \
    __builtin_amdgcn_s_barrier();                              \
} while (0)

__device__ __forceinline__ void stage16(const float* g, float* l) {
    __builtin_amdgcn_global_load_lds(
        (const __attribute__((address_space(1))) void*)g,
        (__attribute__((address_space(3))) void*)l, 16, 0, 0);
}

__global__ __launch_bounds__(BDIM, 4) void engram_shortconv_v11(
    const float* __restrict__ x,
    const float* __restrict__ nw,
    const float* __restrict__ cw,
    float* __restrict__ out)
{
    __shared__ float s_buf[3][ST][D];      // 24 KiB triple-buffered x
    __shared__ float s_part[PAD][4];       // 96 B wave-partials (halo)
    __shared__ float s_inv2[2][ST];
    __shared__ float s_invh[PAD];

    // Bijective XCD-chunked swizzle (512 blocks, 8 XCDs): L-neighbor
    // (halo-sharing) blocks land on the same XCD's L2.
    const int lblk = (blockIdx.x & 7) * CPX + (blockIdx.x >> 3);
    const int t    = lblk % NT;
    const int hc   = (lblk / NT) % HC;
    const int b    = lblk / (NT * HC);
    const int l0   = t * CL;

    const int tid  = threadIdx.x;
    const int wave = tid >> 6;
    const int lane = tid & 63;

    const size_t rs = (size_t)HC * D;
    const float* xcol = x   + ((size_t)b * L * HC + (size_t)hc) * D + tid * 4;
    float*       ocol = out + ((size_t)b * L * HC + (size_t)hc) * D + tid * 4;

    // ---- issue order matters for vmcnt: weights(5), halo(6), stages(6) ----
    const float4 nw4 = *(const float4*)(nw + (size_t)hc * D + tid * 4);
    float4 cwv[4];
    #pragma unroll
    for (int j = 0; j < 4; ++j)
        cwv[j] = *(const float4*)(cw + ((size_t)hc * D + tid * 4 + j) * KW);

    float win[PAD][4];   // halo rows l0-6 .. l0-1
    #pragma unroll
    for (int r = 0; r < PAD; ++r) {
        const int l = l0 - PAD + r;
        float4 v = make_float4(0.f, 0.f, 0.f, 0.f);
        if (l >= 0) v = *(const float4*)(xcol + (size_t)l * rs);
        win[r][0] = v.x; win[r][1] = v.y; win[r][2] = v.z; win[r][3] = v.w;
    }

    #pragma unroll
    for (int s = 0; s < 3; ++s)
        #pragma unroll
        for (int r = 0; r < ST; ++r)
            stage16(xcol + (size_t)(l0 + s * ST + r) * rs, &s_buf[s][r][wave * 256]);

    // fold norm gain into conv taps
    float wk[4][4];
    {
        const float gv[4] = { nw4.x, nw4.y, nw4.z, nw4.w };
        #pragma unroll
        for (int j = 0; j < 4; ++j) {
            wk[j][0] = cwv[j].x * gv[j]; wk[j][1] = cwv[j].y * gv[j];
            wk[j][2] = cwv[j].z * gv[j]; wk[j][3] = cwv[j].w * gv[j];
        }
    }

    // ---- halo RMS: shfl-first (tiny LDS), halo read exactly once ----
    #pragma unroll
    for (int r = 0; r < PAD; ++r) {
        float ss = fmaf(win[r][0], win[r][0], fmaf(win[r][1], win[r][1],
                   fmaf(win[r][2], win[r][2], win[r][3] * win[r][3])));
        #pragma unroll
        for (int off = 32; off >= 1; off >>= 1) ss += __shfl_xor(ss, off);
        if (lane == 0) s_part[r][wave] = ss;
    }
    LGKM_BARRIER();
    if (wave == 0 && lane < PAD) {
        const float s = s_part[lane][0] + s_part[lane][1]
                      + s_part[lane][2] + s_part[lane][3];
        s_invh[lane] = rsqrtf(s * (1.0f / D) + EPS);
    }
    LGKM_BARRIER();
    #pragma unroll
    for (int r = 0; r < PAD; ++r) {
        const float iv = s_invh[r];
        win[r][0] *= iv; win[r][1] *= iv; win[r][2] *= iv; win[r][3] *= iv;
    }

    // stages 0,1 retired (stage2 may fly); cross-wave visible after barrier
    asm volatile("s_waitcnt vmcnt(2)" ::: "memory");
    __builtin_amdgcn_s_barrier();
    {   // seed s_inv2[0][0..1] from buf0 (waves 0,2 -> row0; 1,3 -> row1)
        const int row = wave & 1;
        const float* rp = &s_buf[0][row][0];
        float ss = 0.0f;
        #pragma unroll
        for (int q = 0; q < 4; ++q) {
            const f32x4 v = *(const f32x4*)(rp + lane * 4 + q * 256);
            ss = fmaf(v.x, v.x, fmaf(v.y, v.y, fmaf(v.z, v.z, fmaf(v.w, v.w, ss))));
        }
        #pragma unroll
        for (int off = 32; off >= 1; off >>= 1) ss += __shfl_xor(ss, off);
        if (lane == 0) s_inv2[0][row] = rsqrtf(ss * (1.0f / D) + EPS);
    }
    LGKM_BARRIER();

    float* p0 = &s_buf[0][0][0];
    float* p1 = &s_buf[1][0][0];
    float* p2 = &s_buf[2][0][0];

    #pragma unroll 1
    for (int s = 0; s < NSTEP; ++s) {
        // (a) reduce-ahead: rows of p1 (= stage(s+1) data) -> s_inv2[(s+1)&1]
        if (s < NSTEP - 1) {
            const int row = wave & 1;
            const float* rp = p1 + row * D;
            float ss = 0.0f;
            #pragma unroll
            for (int q = 0; q < 4; ++q) {
                const f32x4 v = *(const f32x4*)(rp + lane * 4 + q * 256);
                ss = fmaf(v.x, v.x, fmaf(v.y, v.y, fmaf(v.z, v.z, fmaf(v.w, v.w, ss))));
            }
            #pragma unroll
            for (int off = 32; off >= 1; off >>= 1) ss += __shfl_xor(ss, off);
            if (lane == 0) s_inv2[(s + 1) & 1][row] = rsqrtf(ss * (1.0f / D) + EPS);
        }

        // (b) conv math for this step's ST rows (own-slice LDS reads only)
        const int base = l0 + s * ST;
        float cur[ST][4];
        #pragma unroll
        for (int r = 0; r < ST; ++r) {
            const f32x4 v = *(const f32x4*)(p0 + r * D + tid * 4);
            const float iv = s_inv2[s & 1][r];
            cur[r][0] = v.x * iv; cur[r][1] = v.y * iv;
            cur[r][2] = v.z * iv; cur[r][3] = v.w * iv;
        }
        float ov[ST][4];
        #pragma unroll
        for (int i = 0; i < ST; ++i) {
            #pragma unroll
            for (int j = 0; j < 4; ++j) {
                float a = 0.0f;
                #pragma unroll
                for (int k = 0; k < 4; ++k) {
                    const int rel = i - 6 + 2 * k;
                    const float xv = (rel < 0) ? win[6 + rel][j] : cur[rel][j];
                    a = fmaf(wk[j][k], xv, a);
                }
                ov[i][j] = a / (1.0f + __expf(-a));
            }
        }

        // (c) rotate halo (scaled)
        #pragma unroll
        for (int r = 0; r < PAD - ST; ++r) {
            win[r][0] = win[r + ST][0]; win[r][1] = win[r + ST][1];
            win[r][2] = win[r + ST][2]; win[r][3] = win[r + ST][3];
        }
        #pragma unroll
        for (int r = 0; r < ST; ++r) {
            win[PAD - ST + r][0] = cur[r][0]; win[PAD - ST + r][1] = cur[r][1];
            win[PAD - ST + r][2] = cur[r][2]; win[PAD - ST + r][3] = cur[r][3];
        }

        // (d) stage(s+3) into p0 (just consumed) — issued BEFORE the stores
        if (s < NSTEP - 3) {
            asm volatile("s_waitcnt lgkmcnt(0)" ::: "memory");
            __builtin_amdgcn_sched_barrier(0);
            #pragma unroll
            for (int r = 0; r < ST; ++r)
                stage16(xcol + (size_t)(l0 + (s + 3) * ST + r) * rs,
                        p0 + r * D + wave * 256);
            __builtin_amdgcn_sched_barrier(0);
        }

        // stores (nontemporal: output never re-read; keep L2/L3 for x)
        #pragma unroll
        for (int i = 0; i < ST; ++i) {
            f32x4 o = { ov[i][0], ov[i][1], ov[i][2], ov[i][3] };
            __builtin_nontemporal_store(o, (f32x4*)(ocol + (size_t)(base + i) * rs));
        }

        // (e) counted vmcnt: stage(s+2) retired; newer ops stay in flight
        if (s < NSTEP - 1) {
            if (s <= NSTEP - 4)      asm volatile("s_waitcnt vmcnt(6)" ::: "memory");
            else if (s == NSTEP - 3) asm volatile("s_waitcnt vmcnt(4)" ::: "memory");
            LGKM_BARRIER();
        }

        float* tmp = p0; p0 = p1; p1 = p2; p2 = tmp;
    }
}

} // namespace

extern "C" void kernel_launch(void* const* d_in, const int* in_sizes, int n_in,
                              void* d_out, int out_size, void* d_ws, size_t ws_size,
                              hipStream_t stream) {
    const float* x  = (const float*)d_in[0];   // [B, L, HC, D] f32
    const float* nw = (const float*)d_in[1];   // [HC, D] f32
    const float* cw = (const float*)d_in[2];   // [C, 1, K] f32
    float* out = (float*)d_out;                // [B, L, HC, D] f32

    engram_shortconv_v11<<<dim3(NBLK), dim3(BDIM), 0, stream>>>(x, nw, cw, out);
}